// Round 1
// baseline (58.220 us; speedup 1.0000x reference)
//
#include <hip/hip_runtime.h>

// NeRF volume rendering: per-ray sort(t) -> dt -> transmittance -> weights ->
// color/depth/wi. One 64-lane wave per ray; lane l holds samples 2l and 2l+1.
// Interleaved layout: bitonic stride-1 passes are in-register; strides>=2 are
// shfl_xor(stride/2); all global accesses are float2-vectorized.

__global__ __launch_bounds__(256) void nerf_render_kernel(
    const float* __restrict__ t,
    const float* __restrict__ sigma,
    const float* __restrict__ c,
    float* __restrict__ out,
    int n_rays) {
  const int wid  = blockIdx.x * 4 + (threadIdx.x >> 6);
  const int lane = threadIdx.x & 63;
  if (wid >= n_rays) return;
  const int ray = wid;

  // ---- load t (float2 per lane: samples 2l, 2l+1) ----
  const float2 t2 = *(const float2*)(t + (size_t)ray * 128 + lane * 2);
  float v0 = t2.x, v1 = t2.y;   // v0 = elem index 2*lane, v1 = 2*lane+1

  // ---- bitonic sort of 128 elements across the wave ----
  // compare-exchange(i, i^stride), ascending block iff (i & size) == 0
#pragma unroll
  for (int size = 2; size <= 128; size <<= 1) {
#pragma unroll
    for (int stride = size >> 1; stride >= 2; stride >>= 1) {
      const int i = 2 * lane;                   // same bits >=1 as 2*lane+1
      const bool up       = ((i & size) == 0);  // size=128 -> always true
      const bool lower    = ((i & stride) == 0);
      const bool keep_min = (lower == up);
      const float p0 = __shfl_xor(v0, stride >> 1);
      const float p1 = __shfl_xor(v1, stride >> 1);
      v0 = keep_min ? fminf(v0, p0) : fmaxf(v0, p0);
      v1 = keep_min ? fminf(v1, p1) : fmaxf(v1, p1);
    }
    { // stride = 1: in-lane between v0 (even idx) and v1 (odd idx)
      const bool up = (((2 * lane) & size) == 0);
      const float lo = fminf(v0, v1), hi = fmaxf(v0, v1);
      v0 = up ? lo : hi;
      v1 = up ? hi : lo;
    }
  }

  // ---- dt (last sample dt = 0) ----
  const float v0n = __shfl(v0, (lane + 1) & 63);  // t[2l+2] for lane<63
  const float dt0 = v1 - v0;
  const float dt1 = (lane == 63) ? 0.0f : (v0n - v1);

  // ---- sigma * dt ----
  const float2 sg = *(const float2*)(sigma + (size_t)ray * 128 + lane * 2);
  const float sdt0 = sg.x * dt0;
  const float sdt1 = sg.y * dt1;

  // ---- exclusive prefix sum of sdt via pair-sum wave scan ----
  const float ps = sdt0 + sdt1;
  float ip = ps;
#pragma unroll
  for (int off = 1; off < 64; off <<= 1) {
    const float n = __shfl_up(ip, off);
    if (lane >= off) ip += n;
  }
  const float excl = ip - ps;        // cumsum of all pairs before this lane
  const float cs0  = excl + sdt0;    // inclusive cumsum at index 2l

  // T_i = exp(-exclusive_cumsum_i); alpha_i = 1 - exp(-sdt_i)
  const float T0  = __expf(-excl);
  const float T1  = __expf(-cs0);
  const float wi0 = T0 * (1.0f - __expf(-sdt0));
  const float wi1 = T1 * (1.0f - __expf(-sdt1));

  // ---- per-lane partials for color (3ch) + depth ----
  const float* cr = c + (size_t)ray * 384 + lane * 6;  // 8B-aligned
  const float2 cA = *(const float2*)(cr);      // c[2l].r,  c[2l].g
  const float2 cB = *(const float2*)(cr + 2);  // c[2l].b,  c[2l+1].r
  const float2 cC = *(const float2*)(cr + 4);  // c[2l+1].g, c[2l+1].b
  float pr = wi0 * cA.x + wi1 * cB.y;
  float pg = wi0 * cA.y + wi1 * cC.x;
  float pb = wi0 * cB.x + wi1 * cC.y;
  float pd = wi0 * v0   + wi1 * v1;     // depth uses sorted t

  // ---- wave reduction (butterfly) ----
#pragma unroll
  for (int off = 32; off >= 1; off >>= 1) {
    pr += __shfl_xor(pr, off);
    pg += __shfl_xor(pg, off);
    pb += __shfl_xor(pb, off);
    pd += __shfl_xor(pd, off);
  }

  // ---- stores ----
  // d_out layout: color [n_rays*3] | depth [n_rays] | wi [n_rays*128]
  float* wi_out = out + (size_t)n_rays * 4 + (size_t)ray * 128 + lane * 2;
  *(float2*)wi_out = make_float2(wi0, wi1);
  if (lane == 0) {
    out[(size_t)ray * 3 + 0] = pr;
    out[(size_t)ray * 3 + 1] = pg;
    out[(size_t)ray * 3 + 2] = pb;
    out[(size_t)n_rays * 3 + ray] = pd;
  }
}

extern "C" void kernel_launch(void* const* d_in, const int* in_sizes, int n_in,
                              void* d_out, int out_size, void* d_ws, size_t ws_size,
                              hipStream_t stream) {
  const float* t     = (const float*)d_in[0];
  const float* sigma = (const float*)d_in[1];
  const float* c     = (const float*)d_in[2];
  float* out = (float*)d_out;
  const int n_rays = in_sizes[0] / 128;
  const int blocks = (n_rays + 3) / 4;  // 4 waves (rays) per 256-thread block
  nerf_render_kernel<<<blocks, 256, 0, stream>>>(t, sigma, c, out, n_rays);
}

// Round 2
// 34.567 us; speedup vs baseline: 1.6842x; 1.6842x over previous
//
#include <hip/hip_runtime.h>

// NeRF volume rendering, 8 samples per lane, 16 lanes per ray, 4 rays/wave.
// Sort: in-lane Batcher-8 (ascending, compile-time network) + 4 bitonic merge
// stages using the reversal formulation (first pass compares i vs 2S-1-i via
// shfl_xor of reversed registers), so every CE keeps min at the lower index.
// Cross-lane passes: 10 total (vs 21 for 2-elem layout), amortized over 4 rays.

#define CEX(a,b) { float mn_=fminf(v[a],v[b]); v[b]=fmaxf(v[a],v[b]); v[a]=mn_; }

// first pass of merge S->2S: partner = reversed regs, lane xor (2S/8-1)
#define CROSS_REV(mask, lowbit) { \
  float w_[8]; \
  _Pragma("unroll") for (int r_=0;r_<8;++r_) w_[r_]=__shfl_xor(v[7-r_], (mask)); \
  const bool lo_ = (gl & (lowbit)) == 0; \
  _Pragma("unroll") for (int r_=0;r_<8;++r_) \
    v[r_] = lo_ ? fminf(v[r_],w_[r_]) : fmaxf(v[r_],w_[r_]); }

// uniform-ascending cross-lane CE pass, stride = 8*mask elements
#define CROSS(mask, lowbit) { \
  float w_[8]; \
  _Pragma("unroll") for (int r_=0;r_<8;++r_) w_[r_]=__shfl_xor(v[r_], (mask)); \
  const bool lo_ = (gl & (lowbit)) == 0; \
  _Pragma("unroll") for (int r_=0;r_<8;++r_) \
    v[r_] = lo_ ? fminf(v[r_],w_[r_]) : fmaxf(v[r_],w_[r_]); }

// in-lane ascending bitonic merge of 8 (strides 4,2,1)
#define INLANE8() { CEX(0,4) CEX(1,5) CEX(2,6) CEX(3,7) \
                    CEX(0,2) CEX(1,3) CEX(4,6) CEX(5,7) \
                    CEX(0,1) CEX(2,3) CEX(4,5) CEX(6,7) }

__global__ __launch_bounds__(256) void nerf_render_kernel(
    const float* __restrict__ t,
    const float* __restrict__ sigma,
    const float* __restrict__ c,
    float* __restrict__ out,
    int n_rays) {
  const int tid  = threadIdx.x;
  const int lane = tid & 63;
  const int gl   = lane & 15;               // lane within the 16-lane ray group
  const int ray  = blockIdx.x * 16 + (tid >> 4);
  if (ray >= n_rays) return;

  // ---- load t: 8 contiguous samples per lane ----
  const float4* tb = (const float4*)(t + (size_t)ray * 128 + gl * 8);
  float v[8];
  { float4 a = tb[0], b = tb[1];
    v[0]=a.x; v[1]=a.y; v[2]=a.z; v[3]=a.w;
    v[4]=b.x; v[5]=b.y; v[6]=b.z; v[7]=b.w; }

  // ---- in-lane Batcher odd-even mergesort of 8 (ascending, 19 CEs) ----
  CEX(0,1) CEX(2,3) CEX(4,5) CEX(6,7)
  CEX(0,2) CEX(1,3) CEX(4,6) CEX(5,7)
  CEX(1,2) CEX(5,6)
  CEX(0,4) CEX(1,5) CEX(2,6) CEX(3,7)
  CEX(2,4) CEX(3,5)
  CEX(1,2) CEX(3,4) CEX(5,6)

  // ---- merge 8->16 ----
  CROSS_REV(1, 1)  INLANE8()
  // ---- merge 16->32 ----
  CROSS_REV(3, 2)  CROSS(1, 1)  INLANE8()
  // ---- merge 32->64 ----
  CROSS_REV(7, 4)  CROSS(2, 2)  CROSS(1, 1)  INLANE8()
  // ---- merge 64->128 ----
  CROSS_REV(15, 8) CROSS(4, 4)  CROSS(2, 2)  CROSS(1, 1)  INLANE8()

  // ---- dt (last sample of ray gets dt = 0) ----
  const float nxt = __shfl(v[0], (lane + 1) & 63);
  float dt[8];
#pragma unroll
  for (int r = 0; r < 7; ++r) dt[r] = v[r + 1] - v[r];
  dt[7] = (gl == 15) ? 0.0f : (nxt - v[7]);

  // ---- sigma * dt ----
  const float4* sb = (const float4*)(sigma + (size_t)ray * 128 + gl * 8);
  float sdt[8];
  { float4 a = sb[0], b = sb[1];
    sdt[0]=a.x*dt[0]; sdt[1]=a.y*dt[1]; sdt[2]=a.z*dt[2]; sdt[3]=a.w*dt[3];
    sdt[4]=b.x*dt[4]; sdt[5]=b.y*dt[5]; sdt[6]=b.z*dt[6]; sdt[7]=b.w*dt[7]; }

  // ---- prefix sums: in-lane inclusive, then 16-lane exclusive scan ----
  float p[8];
  p[0] = sdt[0];
#pragma unroll
  for (int r = 1; r < 8; ++r) p[r] = p[r - 1] + sdt[r];
  float s = p[7];
#pragma unroll
  for (int off = 1; off < 16; off <<= 1) {
    const float u = __shfl_up(s, off);
    if (gl >= off) s += u;
  }
  const float excl = s - p[7];   // sum of all sdt before this lane's 8 samples

  // ---- weights: wi_i = exp(-cum_excl_i) - exp(-cum_incl_i) ----
  float wi[8];
  float Eprev = __expf(-excl);
#pragma unroll
  for (int r = 0; r < 8; ++r) {
    const float Er = __expf(-(excl + p[r]));
    wi[r] = Eprev - Er;
    Eprev = Er;
  }

  // ---- color / depth partials ----
  float carr[24];
  { const float4* cb = (const float4*)(c + (size_t)ray * 384 + gl * 24);
#pragma unroll
    for (int q = 0; q < 6; ++q) *(float4*)&carr[q * 4] = cb[q]; }
  float pr = 0.f, pg = 0.f, pb = 0.f, pd = 0.f;
#pragma unroll
  for (int r = 0; r < 8; ++r) {
    pr += wi[r] * carr[3 * r + 0];
    pg += wi[r] * carr[3 * r + 1];
    pb += wi[r] * carr[3 * r + 2];
    pd += wi[r] * v[r];
  }

  // ---- 16-lane butterfly reduction ----
#pragma unroll
  for (int m = 8; m >= 1; m >>= 1) {
    pr += __shfl_xor(pr, m);
    pg += __shfl_xor(pg, m);
    pb += __shfl_xor(pb, m);
    pd += __shfl_xor(pd, m);
  }

  // ---- stores: out = color [N*3] | depth [N] | wi [N*128] ----
  float* wo = out + (size_t)n_rays * 4 + (size_t)ray * 128 + gl * 8;
  *(float4*)(wo)     = make_float4(wi[0], wi[1], wi[2], wi[3]);
  *(float4*)(wo + 4) = make_float4(wi[4], wi[5], wi[6], wi[7]);
  if (gl == 0) {
    out[(size_t)ray * 3 + 0] = pr;
    out[(size_t)ray * 3 + 1] = pg;
    out[(size_t)ray * 3 + 2] = pb;
    out[(size_t)n_rays * 3 + ray] = pd;
  }
}

extern "C" void kernel_launch(void* const* d_in, const int* in_sizes, int n_in,
                              void* d_out, int out_size, void* d_ws, size_t ws_size,
                              hipStream_t stream) {
  const float* t     = (const float*)d_in[0];
  const float* sigma = (const float*)d_in[1];
  const float* c     = (const float*)d_in[2];
  float* out = (float*)d_out;
  const int n_rays = in_sizes[0] / 128;
  const int blocks = (n_rays + 15) / 16;   // 16 rays per 256-thread block
  nerf_render_kernel<<<blocks, 256, 0, stream>>>(t, sigma, c, out, n_rays);
}